// Round 13
// baseline (5128.352 us; speedup 1.0000x reference)
//
#include <hip/hip_runtime.h>
#include <cstdint>

// ---------------- problem constants ----------------
constexpr int B_ = 4, N_ = 16384, M_ = 2048;
constexpr int COLS0 = B_ * M_ * 32;   // 262144
constexpr int COLS1 = B_ * M_ * 64;   // 524288

// ---------------- workspace layout (bytes) ----------------
constexpr size_t OFF_NEWXYZ = 0;                                   // B*3*M fp32
constexpr size_t OFF_NIDX0  = (size_t)B_ * 3 * M_ * 4;             // 98304
constexpr size_t OFF_NIDX1  = OFF_NIDX0 + (size_t)COLS0 * 4;
constexpr size_t OFF_STATS  = OFF_NIDX1 + (size_t)COLS1 * 4;
constexpr size_t STATS_VALS = 64 * 2 * 128;                        // doubles per layer region
constexpr size_t OFF_COEF   = OFF_STATS + 6 * STATS_VALS * 8;      // 6 x 128 float4
constexpr size_t OFF_MNMX   = OFF_COEF + 6 * 128 * 16;             // 4 x (B*M*128) fp32 = 16MB
constexpr size_t MNMX_ONE   = (size_t)B_ * M_ * 128 * 4;
constexpr size_t OFF_PROG   = OFF_MNMX + 4 * MNMX_ONE;             // 4 x 64B progress lines
constexpr size_t OFF_Z      = OFF_PROG + 256;
constexpr int ZSTRIDE = 96 * 64;                                   // floats per record

// ---------------- per-channel stats: fp32 butterfly partials -> f64 bucketed atomics ----------
__device__ __forceinline__ void stat_accum(float acc, int o, int cout, double* stats,
                                           int part, int lane) {
  float v1 = acc, v2 = acc * acc;
#pragma unroll
  for (int off = 1; off < 64; off <<= 1) {
    v1 += __shfl_xor(v1, off);
    v2 += __shfl_xor(v2, off);
  }
  if (lane == 0) {
    atomicAdd(stats + ((size_t)part * 2 + 0) * cout + o, (double)v1);
    atomicAdd(stats + ((size_t)part * 2 + 1) * cout + o, (double)v2);
  }
}

// ---------------- conv sweeps: LDS tile + uniform sgpr weight base ---------------------------
template <int CIN, int G>
__device__ __forceinline__ void conv_sweep(const float* __restrict__ w, int o0,
                                           const float* sx, int lane, float* acc) {
  int o0u = __builtin_amdgcn_readfirstlane(o0);       // exact: o0 is wave-uniform
  const float* wb = w + (size_t)o0u * CIN;            // SGPR base -> s_load weights
#pragma unroll
  for (int k = 0; k < G; ++k) acc[k] = 0.f;
#pragma unroll 8
  for (int c = 0; c < CIN; ++c) {
    float xv = sx[c * 64 + lane];
#pragma unroll
    for (int k = 0; k < G; ++k) acc[k] += wb[(size_t)(4 * k) * CIN + c] * xv;
  }
}

// 8-wave variant (mega convL0 role): wave wid owns outs o = wid + 8k.
template <int CIN>
__device__ __forceinline__ void conv_sweep8(const float* __restrict__ w, int o0,
                                            const float* sx, int lane, float* acc) {
  int o0u = __builtin_amdgcn_readfirstlane(o0);
  const float* wb = w + (size_t)o0u * CIN;
#pragma unroll
  for (int k = 0; k < 8; ++k) acc[k] = 0.f;
#pragma unroll 8
  for (int c = 0; c < CIN; ++c) {
    float xv = sx[c * 64 + lane];
#pragma unroll
    for (int k = 0; k < 8; ++k) acc[k] += wb[(size_t)(8 * k) * CIN + c] * xv;
  }
}

// ---------------- ball query wave body (verbatim arithmetic; atomicExch writes) --------------
template <int KNB>
__device__ void bq_wave(const float* __restrict__ xyz, int* __restrict__ nidx,
                        int q, int b, float cx, float cy, float cz, float r2, int lane) {
#pragma clang fp contract(off)
  const float* xb = xyz + (size_t)b * 3 * N_;
  float sqc = (cx * cx + cy * cy) + cz * cz;         // no fma
  int found = 0, first = 0;
  for (int c = 0; c < N_ / 64; ++c) {
    int n = c * 64 + lane;
    float x = xb[n], y = xb[N_ + n], z = xb[2 * N_ + n];
    float sqx = (x * x + y * y) + z * z;             // no fma
    float dot = fmaf(cz, z, fmaf(cy, y, cx * x));    // fma chain (proven ref rounding)
    float d2 = (sqc + sqx) - 2.0f * dot;
    bool in = d2 < r2;
    unsigned long long mask = __ballot(in);
    if (mask) {
      if (found == 0) first = c * 64 + (__ffsll((long long)mask) - 1);
      int pos = found + __popcll(mask & ((1ull << lane) - 1ull));
      if (in && pos < KNB) atomicExch(&nidx[(size_t)q * KNB + pos], n);  // coherent write
      found += __popcll(mask);
      if (found >= KNB) break;
    }
  }
  if (found < KNB) {
    int fill = (found == 0) ? 0 : first;
    for (int s2 = found + lane; s2 < KNB; s2 += 64) atomicExch(&nidx[(size_t)q * KNB + s2], fill);
  }
}

// ---------------- MEGA kernel: fps (0-3) + bq (4-51) + scale1-convL0 (52-255) ----------------
// R12 post-mortem: publish-batching bought only ~25us -> the cost is POLL-QUEUE CONTENTION:
// 384 bq waves RMW-poll the very data lines fps publishes into; each fps atomicExch queues
// behind hundreds of pending polls. R13: decouple -- consumers poll a per-batch PROGRESS word
// (own 64B line); fps bumps it once per 8 steps AFTER an explicit vmcnt(0) drain (data atomics
// at coherence before prog). Data reads become ONE-SHOT atomicAdd(p,0) after the prog gate.
// Ordering: producer data-RMW -> vmcnt(0) -> prog-RMW; consumer prog-gate -> data-RMW.
// All polls capped + s_sleep backoff -> failure = visible mismatch, never a hang.
__global__ __launch_bounds__(512, 2) void mega_kernel(
    const float* __restrict__ xyz, const float* __restrict__ feat,
    float* __restrict__ newxyz, float* __restrict__ outxyz,
    int* __restrict__ nidx0, int* __restrict__ nidx1,
    float* __restrict__ Z, double* __restrict__ st3, const float* __restrict__ w10,
    unsigned* __restrict__ prog) {
  __shared__ __align__(16) char smem[98304];
  int bid = blockIdx.x, t = threadIdx.x, lane = t & 63, wid = t >> 6;

  if (bid < 4) {
    // ================= FPS role (R9-verbatim arithmetic + batched pub + progress word) ======
#pragma clang fp contract(off)
    float* s_out = (float*)smem;                                   // 3*M floats (24576B)
    unsigned long long* s_red = (unsigned long long*)(smem + 24576);
    int* s_w = (int*)(smem + 24640);
    int b = bid;
    unsigned* pg = prog + (size_t)b * 16;                          // own 64B line
    const float* xb = xyz + (size_t)b * 3 * N_;
    float px[32], py[32], pz[32], dd[32];
#pragma unroll
    for (int i = 0; i < 32; ++i) {
      int n = t + (i << 9);
      px[i] = xb[n]; py[i] = xb[N_ + n]; pz[i] = xb[2 * N_ + n];
      dd[i] = 1e10f;
      asm volatile("" : "+v"(px[i]), "+v"(py[i]), "+v"(pz[i]));
    }
    size_t base = (size_t)b * 3 * M_;
    float fx = xb[0], fy = xb[N_], fz = xb[2 * N_];
    if (t == 0) {
      s_out[0] = fx; s_out[M_] = fy; s_out[2 * M_] = fz;
      atomicExch(&newxyz[base], fx); atomicExch(&newxyz[base + M_], fy);
      atomicExch(&newxyz[base + 2 * M_], fz);
      asm volatile("s_waitcnt vmcnt(0)" ::: "memory");             // data at coherence
      atomicExch(pg, 1u);                                          // center 0 readable
    }
    for (int s = 1; s < M_; ++s) {
      float bv = -1.f; int bi = 0;
#pragma unroll
      for (int i = 0; i < 32; ++i) {
        float dx = px[i] - fx, dy = py[i] - fy, dz = pz[i] - fz;
        float d = (dx * dx + dy * dy) + dz * dz;   // verbatim ref arithmetic (no FMA)
        float dm = dd[i];
        if (d < dm) dm = d;
        dd[i] = dm;
        if (dm > bv) { bv = dm; bi = t + (i << 9); }
      }
      unsigned long long key =
          ((unsigned long long)__float_as_uint(bv) << 32) | (unsigned)(0xFFFFFFFFu - (unsigned)bi);
#pragma unroll
      for (int off = 1; off < 64; off <<= 1) {
        unsigned long long o = __shfl_xor(key, off);
        if (o > key) key = o;
      }
      if (lane == 0) s_red[wid] = key;
      __syncthreads();
      if (wid == 0) {
        unsigned long long k2 = (lane < 8) ? s_red[lane] : 0ull;
#pragma unroll
        for (int off = 1; off < 8; off <<= 1) {
          unsigned long long o = __shfl_xor(k2, off);
          if (o > k2) k2 = o;
        }
        if (lane == 0) *s_w = (int)(0xFFFFFFFFu - (unsigned)(k2 & 0xFFFFFFFFull));
        if ((s & 7) == 0) {                      // publish centers [s-8, s-1], then prog = s
          if (lane < 24) {
            int st = (s - 8) + lane / 3, cd = lane % 3;
            atomicExch(&newxyz[base + (size_t)cd * M_ + st], s_out[(size_t)cd * M_ + st]);
          }
          asm volatile("s_waitcnt vmcnt(0)" ::: "memory");
          if (lane == 0) atomicExch(pg, (unsigned)s);
        }
      }
      __syncthreads();
      int w = *s_w;
      fx = xb[w]; fy = xb[N_ + w]; fz = xb[2 * N_ + w];
      if (t == 0) { s_out[s] = fx; s_out[M_ + s] = fy; s_out[2 * M_ + s] = fz; }
    }
    __syncthreads();
    // tail: centers 2040..2047, then prog = 2048
    if (wid == 0) {
      if (lane < 24) {
        int st = 2040 + lane / 3, cd = lane % 3;
        atomicExch(&newxyz[base + (size_t)cd * M_ + st], s_out[(size_t)cd * M_ + st]);
      }
      asm volatile("s_waitcnt vmcnt(0)" ::: "memory");
      if (lane == 0) atomicExch(pg, 2048u);
    }
    for (int e = t; e < 3 * M_; e += 512) outxyz[base + e] = s_out[e];  // d_out copy
  } else if (bid < 52) {
    // ================= BQ role: poll PROG (1 lane), one-shot data reads =====================
    int waveId = (bid - 4) * 8 + wid;
    for (int T = waveId; T < 2 * B_ * M_; T += 48 * 8) {
      int mg = T >> 1;                           // global center 0..8191
      int b = mg >> 11, m = mg & 2047;
      unsigned* pg = prog + (size_t)b * 16;
      if (lane == 0) {
        for (int it = 0; it < (1 << 18); ++it) {
          unsigned pv = atomicAdd(pg, 0u);       // coherent read of progress
          if (pv > (unsigned)m) break;
          __builtin_amdgcn_s_sleep(32);
        }
      }                                          // wave64 lockstep: all lanes gated by lane 0
      unsigned vv = 0;
      if (lane < 3)                              // ONE-SHOT coherent data read (no polling)
        vv = atomicAdd((unsigned*)(newxyz + ((size_t)b * 3 + lane) * M_ + m), 0u);
      float cx = __uint_as_float(__shfl((int)vv, 0));
      float cy = __uint_as_float(__shfl((int)vv, 1));
      float cz = __uint_as_float(__shfl((int)vv, 2));
      if (T & 1) bq_wave<64>(xyz, nidx1, mg, b, cx, cy, cz, (float)(0.4 * 0.4), lane);
      else       bq_wave<32>(xyz, nidx0, mg, b, cx, cy, cz, (float)(0.2 * 0.2), lane);
    }
  } else {
    // ================= scale1 convL0 role: 204 blocks sweep 8192 records ====================
    float* sx   = (float*)smem;                  // 67*64 floats
    int*   snb  = (int*)(smem + 17152);
    float* sctr = (float*)(smem + 17152 + 256);
    for (int R = bid - 52; R < COLS1 / 64; R += 204) {
      __syncthreads();                           // protect snb/sx from previous record
      if (wid == 0) {
        int* p = nidx1 + (size_t)R * 64 + lane;
        int v = -1;
        for (int it = 0; it < (1 << 18); ++it) {
          v = atomicAdd(p, 0);                   // coherent read; valid entries 0..16383
          if (v != -1) break;
          __builtin_amdgcn_s_sleep(64);
        }
        snb[lane] = (v < 0) ? 0 : v;
        if (lane < 3) {                          // coords valid once nidx row complete
          int b = R >> 11, m = R & 2047;
          sctr[lane] = __uint_as_float(
              atomicAdd((unsigned*)(newxyz + ((size_t)b * 3 + lane) * M_ + m), 0u));
        }
      }
      __syncthreads();
      int b = R >> 11;
      for (int e = t; e < 67 * 64; e += 512) {
        int c = e >> 6, l = e & 63;
        int n = snb[l];
        float v;
        if (c < 3) v = xyz[((size_t)b * 3 + c) * N_ + n] - sctr[c];
        else       v = feat[((size_t)b * 64 + (c - 3)) * N_ + n];
        sx[e] = v;
      }
      __syncthreads();
      float* zr = Z + (size_t)R * ZSTRIDE;
      int part = R & 63;
      float acc[8];
      conv_sweep8<67>(w10, wid, sx, lane, acc);  // outs o = wid + 8k
#pragma unroll
      for (int k = 0; k < 8; ++k) {
        int o = wid + 8 * k;
        zr[o * 64 + lane] = acc[k];
        stat_accum(acc[k], o, 64, st3, part, lane);
      }
    }
  }
}

// ---------------- stage BN(ReLU(zr)) tile -> sx, float4 path ---------------------------------
template <int CIN>
__device__ __forceinline__ void stage_bn(const float* __restrict__ zr,
                                         const float4* __restrict__ coefIn,
                                         float* sx, int t) {
  const float4* zr4 = (const float4*)zr;
  float4* sx4 = (float4*)sx;
  for (int e = t; e < CIN * 16; e += 256) {
    int c = e >> 4;
    float4 v = zr4[e];
    float4 cf = coefIn[c];
    float4 r;
    r.x = fmaxf(((v.x - cf.x) * cf.y) * cf.z + cf.w, 0.f);
    r.y = fmaxf(((v.y - cf.x) * cf.y) * cf.z + cf.w, 0.f);
    r.z = fmaxf(((v.z - cf.x) * cf.y) * cf.z + cf.w, 0.f);
    r.w = fmaxf(((v.w - cf.x) * cf.y) * cf.z + cf.w, 0.f);
    sx4[e] = r;
  }
}

// ---------------- scale0 layer 0 (post-mega, R9-proven 4-wave version) -----------------------
template <int KNB>
__global__ __launch_bounds__(256) void convL0_kernel(
    const float* __restrict__ w0, const float* __restrict__ xyz,
    const float* __restrict__ feat, const int* __restrict__ nidx,
    const float* __restrict__ newxyz, float* __restrict__ Z, double* __restrict__ stats) {
  __shared__ float sx[67 * 64];
  __shared__ int snb[64];
  int rec = blockIdx.x, t = threadIdx.x, lane = t & 63, wid = t >> 6;
  if (t < 64) snb[t] = nidx[(size_t)rec * 64 + t];
  __syncthreads();
  for (int e = t; e < 67 * 64; e += 256) {
    int c = e >> 6, l = e & 63;
    int col = rec * 64 + l;
    int b = col / (M_ * KNB);
    int rem = col - b * (M_ * KNB);
    int m = rem / KNB;
    int n = snb[l];
    float v;
    if (c < 3) v = xyz[((size_t)b * 3 + c) * N_ + n] - newxyz[((size_t)b * 3 + c) * M_ + m];
    else       v = feat[((size_t)b * 64 + (c - 3)) * N_ + n];
    sx[e] = v;
  }
  __syncthreads();
  float* zr = Z + (size_t)rec * ZSTRIDE;
  int part = rec & 63;
  float acc[8];
#pragma unroll
  for (int g = 0; g < 2; ++g) {
    int o0 = wid + 32 * g;
    conv_sweep<67, 8>(w0, o0, sx, lane, acc);
#pragma unroll
    for (int k = 0; k < 8; ++k) {
      int o = o0 + 4 * k;
      zr[o * 64 + lane] = acc[k];
      stat_accum(acc[k], o, 64, stats, part, lane);
    }
  }
}

// ---------------- mid layer: BN-stage -> conv -> in-place store + stats ----------------------
template <int CIN, int COUT>
__global__ __launch_bounds__(256) void convMid_kernel(
    const float* __restrict__ w, const float4* __restrict__ coefIn,
    float* __restrict__ Z, double* __restrict__ stats) {
  __shared__ float sx[CIN * 64];
  int rec = blockIdx.x, t = threadIdx.x, lane = t & 63, wid = t >> 6;
  float* zr = Z + (size_t)rec * ZSTRIDE;
  stage_bn<CIN>(zr, coefIn, sx, t);
  __syncthreads();
  int part = rec & 63;
  float acc[8];
#pragma unroll
  for (int g = 0; g < COUT / 32; ++g) {
    int o0 = wid + 32 * g;
    conv_sweep<CIN, 8>(w, o0, sx, lane, acc);
#pragma unroll
    for (int k = 0; k < 8; ++k) {
      int o = o0 + 4 * k;
      zr[o * 64 + lane] = acc[k];
      stat_accum(acc[k], o, COUT, stats, part, lane);
    }
  }
}

// ---------------- last layer (single pass): conv + stats + raw min/max over K ----------------
template <int CIN, int KNB>
__global__ __launch_bounds__(256) void convLast_kernel(
    const float* __restrict__ w, const float4* __restrict__ coefIn,
    const float* __restrict__ Z, double* __restrict__ stats,
    float* __restrict__ mx, float* __restrict__ mn) {
  __shared__ float sx[CIN * 64];
  int rec = blockIdx.x, t = threadIdx.x, lane = t & 63, wid = t >> 6;
  const float* zr = Z + (size_t)rec * ZSTRIDE;
  stage_bn<CIN>(zr, coefIn, sx, t);
  __syncthreads();
  int part = rec & 63;
  float acc[8];
#pragma unroll
  for (int g = 0; g < 4; ++g) {
    int o0 = wid + 32 * g;
    conv_sweep<CIN, 8>(w, o0, sx, lane, acc);
#pragma unroll
    for (int k = 0; k < 8; ++k) {
      int o = o0 + 4 * k;
      stat_accum(acc[k], o, 128, stats, part, lane);
      float vM = acc[k], vN = acc[k];
      if (KNB == 64) {
#pragma unroll
        for (int off = 1; off < 64; off <<= 1) {
          vM = fmaxf(vM, __shfl_xor(vM, off));
          vN = fminf(vN, __shfl_xor(vN, off));
        }
        if (lane == 0) {
          mx[(size_t)o * (B_ * M_) + rec] = vM;
          mn[(size_t)o * (B_ * M_) + rec] = vN;
        }
      } else {
#pragma unroll
        for (int off = 1; off < 32; off <<= 1) {
          vM = fmaxf(vM, __shfl_xor(vM, off));
          vN = fminf(vN, __shfl_xor(vN, off));
        }
        if ((lane & 31) == 0) {
          int grp = rec * 2 + (lane >> 5);
          mx[(size_t)o * (B_ * M_) + grp] = vM;
          mn[(size_t)o * (B_ * M_) + grp] = vN;
        }
      }
    }
  }
}

// ---------------- finalize: out = ReLU(fmax(BN(mx), BN(mn))), ref op order -------------------
__global__ __launch_bounds__(256) void pool_fin_kernel(
    const float* __restrict__ mx, const float* __restrict__ mn,
    const float4* __restrict__ coefOut, float* __restrict__ outFeats, int chBase) {
  int idx = blockIdx.x * 256 + threadIdx.x;     // < 128 * B*M
  int o = idx >> 13;
  int gm = idx & 8191;
  float4 cf = coefOut[o];
  float vM = mx[idx], vN = mn[idx];
  float rM = ((vM - cf.x) * cf.y) * cf.z + cf.w;
  float rN = ((vN - cf.x) * cf.y) * cf.z + cf.w;
  float z = fmaxf(fmaxf(rM, rN), 0.f);
  int b = gm >> 11, m = gm & 2047;
  outFeats[((size_t)b * 256 + chBase + o) * M_ + m] = z;
}

// ---------------- fold fp64 BN stats into per-channel (mu, rstd, g, b) ----------------
__global__ void coef_kernel(const double* __restrict__ stats, const float* __restrict__ g,
                            const float* __restrict__ bb, float4* __restrict__ coef,
                            int cout, double invcnt) {
  int ch = threadIdx.x;
  if (ch >= cout) return;
  double s1 = 0.0, s2 = 0.0;
  for (int p = 0; p < 64; ++p) {
    s1 += stats[((size_t)p * 2 + 0) * cout + ch];
    s2 += stats[((size_t)p * 2 + 1) * cout + ch];
  }
  double mean = s1 * invcnt;
  double var = s2 * invcnt - mean * mean;
  double rstd = 1.0 / sqrt(var + 1e-5);
  coef[ch] = make_float4((float)mean, (float)rstd, g[ch], bb[ch]);
}

// ---------------- launcher ----------------
extern "C" void kernel_launch(void* const* d_in, const int* in_sizes, int n_in,
                              void* d_out, int out_size, void* d_ws, size_t ws_size,
                              hipStream_t stream) {
  const float* xyz  = (const float*)d_in[0];
  const float* feat = (const float*)d_in[1];
  const float* w00 = (const float*)d_in[2],  *g00 = (const float*)d_in[3],  *b00 = (const float*)d_in[4];
  const float* w01 = (const float*)d_in[5],  *g01 = (const float*)d_in[6],  *b01 = (const float*)d_in[7];
  const float* w02 = (const float*)d_in[8],  *g02 = (const float*)d_in[9],  *b02 = (const float*)d_in[10];
  const float* w10 = (const float*)d_in[11], *g10 = (const float*)d_in[12], *b10 = (const float*)d_in[13];
  const float* w11 = (const float*)d_in[14], *g11 = (const float*)d_in[15], *b11 = (const float*)d_in[16];
  const float* w12 = (const float*)d_in[17], *g12 = (const float*)d_in[18], *b12 = (const float*)d_in[19];

  char* ws = (char*)d_ws;
  float*  newxyz = (float*)(ws + OFF_NEWXYZ);
  int*    nidx0  = (int*)(ws + OFF_NIDX0);
  int*    nidx1  = (int*)(ws + OFF_NIDX1);
  double* stats  = (double*)(ws + OFF_STATS);
  float4* coef   = (float4*)(ws + OFF_COEF);
  float*  mx0    = (float*)(ws + OFF_MNMX + 0 * MNMX_ONE);
  float*  mn0    = (float*)(ws + OFF_MNMX + 1 * MNMX_ONE);
  float*  mx1    = (float*)(ws + OFF_MNMX + 2 * MNMX_ONE);
  float*  mn1    = (float*)(ws + OFF_MNMX + 3 * MNMX_ONE);
  unsigned* prog = (unsigned*)(ws + OFF_PROG);
  float*  Z      = (float*)(ws + OFF_Z);
  float* outF = (float*)d_out;
  float* outFeats = outF + (size_t)B_ * 3 * M_;

  float4* c00 = coef + 0 * 128; float4* c01 = coef + 1 * 128; float4* c02 = coef + 2 * 128;
  float4* c10 = coef + 3 * 128; float4* c11 = coef + 4 * 128; float4* c12 = coef + 5 * 128;
  double* st0 = stats + 0 * STATS_VALS; double* st1 = stats + 1 * STATS_VALS;
  double* st2 = stats + 2 * STATS_VALS; double* st3 = stats + 3 * STATS_VALS;
  double* st4 = stats + 4 * STATS_VALS; double* st5 = stats + 5 * STATS_VALS;
  int gb0 = COLS0 / 64, gb1 = COLS1 / 64;
  int gfin = (128 * B_ * M_) / 256;

  // sentinels + stats + progress (graph-safe, re-armed every replay)
  hipMemsetAsync(ws + OFF_STATS, 0, 6 * STATS_VALS * 8, stream);
  hipMemsetAsync(newxyz, 0xFF, (size_t)B_ * 3 * M_ * 4, stream);   // NaN bits = "not ready"
  hipMemsetAsync(nidx1, 0xFF, (size_t)COLS1 * 4, stream);          // -1 = "not ready"
  hipMemsetAsync(ws + OFF_PROG, 0, 256, stream);                   // prog = 0

  // mega: fps + bq(both radii) + scale1 convL0, overlapped
  mega_kernel<<<256, 512, 0, stream>>>(xyz, feat, newxyz, outF, nidx0, nidx1, Z, st3, w10, prog);

  // ---- scale 1 first (Z holds its L0 output): 64->96->128 ----
  coef_kernel<<<1, 128, 0, stream>>>(st3, g10, b10, c10, 64, 1.0 / COLS1);
  convMid_kernel<64, 96><<<gb1, 256, 0, stream>>>(w11, c10, Z, st4);
  coef_kernel<<<1, 128, 0, stream>>>(st4, g11, b11, c11, 96, 1.0 / COLS1);
  convLast_kernel<96, 64><<<gb1, 256, 0, stream>>>(w12, c11, Z, st5, mx1, mn1);
  coef_kernel<<<1, 128, 0, stream>>>(st5, g12, b12, c12, 128, 1.0 / COLS1);
  pool_fin_kernel<<<gfin, 256, 0, stream>>>(mx1, mn1, c12, outFeats, 128);

  // ---- scale 0 (reuses Z after scale1 consumed it): 67->64->64->128 ----
  convL0_kernel<32><<<gb0, 256, 0, stream>>>(w00, xyz, feat, nidx0, newxyz, Z, st0);
  coef_kernel<<<1, 128, 0, stream>>>(st0, g00, b00, c00, 64, 1.0 / COLS0);
  convMid_kernel<64, 64><<<gb0, 256, 0, stream>>>(w01, c00, Z, st1);
  coef_kernel<<<1, 128, 0, stream>>>(st1, g01, b01, c01, 64, 1.0 / COLS0);
  convLast_kernel<64, 32><<<gb0, 256, 0, stream>>>(w02, c01, Z, st2, mx0, mn0);
  coef_kernel<<<1, 128, 0, stream>>>(st2, g02, b02, c02, 128, 1.0 / COLS0);
  pool_fin_kernel<<<gfin, 256, 0, stream>>>(mx0, mn0, c02, outFeats, 0);
}

// Round 14
// 5001.221 us; speedup vs baseline: 1.0254x; 1.0254x over previous
//
#include <hip/hip_runtime.h>
#include <cstdint>

// ---------------- problem constants ----------------
constexpr int B_ = 4, N_ = 16384, M_ = 2048;
constexpr int COLS0 = B_ * M_ * 32;   // 262144
constexpr int COLS1 = B_ * M_ * 64;   // 524288

// ---------------- workspace layout (bytes) ----------------
constexpr size_t OFF_NEWXYZ = 0;                                   // B*3*M fp32
constexpr size_t OFF_NIDX0  = (size_t)B_ * 3 * M_ * 4;             // 98304
constexpr size_t OFF_NIDX1  = OFF_NIDX0 + (size_t)COLS0 * 4;
constexpr size_t OFF_STATS  = OFF_NIDX1 + (size_t)COLS1 * 4;
constexpr size_t STATS_VALS = 64 * 2 * 128;                        // doubles per layer region
constexpr size_t OFF_COEF   = OFF_STATS + 6 * STATS_VALS * 8;      // 6 x 128 float4
constexpr size_t OFF_MNMX   = OFF_COEF + 6 * 128 * 16;             // 4 x (B*M*128) fp32 = 16MB
constexpr size_t MNMX_ONE   = (size_t)B_ * M_ * 128 * 4;
constexpr size_t OFF_Z      = OFF_MNMX + 4 * MNMX_ONE;
constexpr int ZSTRIDE = 96 * 64;                                   // floats per record

// ---------------- per-channel stats: fp32 butterfly partials -> f64 bucketed atomics ----------
__device__ __forceinline__ void stat_accum(float acc, int o, int cout, double* stats,
                                           int part, int lane) {
  float v1 = acc, v2 = acc * acc;
#pragma unroll
  for (int off = 1; off < 64; off <<= 1) {
    v1 += __shfl_xor(v1, off);
    v2 += __shfl_xor(v2, off);
  }
  if (lane == 0) {
    atomicAdd(stats + ((size_t)part * 2 + 0) * cout + o, (double)v1);
    atomicAdd(stats + ((size_t)part * 2 + 1) * cout + o, (double)v2);
  }
}

// ---------------- conv sweeps: LDS tile + uniform sgpr weight base ---------------------------
template <int CIN, int G>
__device__ __forceinline__ void conv_sweep(const float* __restrict__ w, int o0,
                                           const float* sx, int lane, float* acc) {
  int o0u = __builtin_amdgcn_readfirstlane(o0);       // exact: o0 is wave-uniform
  const float* wb = w + (size_t)o0u * CIN;            // SGPR base -> s_load weights
#pragma unroll
  for (int k = 0; k < G; ++k) acc[k] = 0.f;
#pragma unroll 8
  for (int c = 0; c < CIN; ++c) {
    float xv = sx[c * 64 + lane];
#pragma unroll
    for (int k = 0; k < G; ++k) acc[k] += wb[(size_t)(4 * k) * CIN + c] * xv;
  }
}

// 8-wave variant (mega convL0 role): wave wid owns outs o = wid + 8k.
template <int CIN>
__device__ __forceinline__ void conv_sweep8(const float* __restrict__ w, int o0,
                                            const float* sx, int lane, float* acc) {
  int o0u = __builtin_amdgcn_readfirstlane(o0);
  const float* wb = w + (size_t)o0u * CIN;
#pragma unroll
  for (int k = 0; k < 8; ++k) acc[k] = 0.f;
#pragma unroll 8
  for (int c = 0; c < CIN; ++c) {
    float xv = sx[c * 64 + lane];
#pragma unroll
    for (int k = 0; k < 8; ++k) acc[k] += wb[(size_t)(8 * k) * CIN + c] * xv;
  }
}

// ---------------- ball query wave body (verbatim arithmetic; atomicExch writes) --------------
template <int KNB>
__device__ void bq_wave(const float* __restrict__ xyz, int* __restrict__ nidx,
                        int q, int b, float cx, float cy, float cz, float r2, int lane) {
#pragma clang fp contract(off)
  const float* xb = xyz + (size_t)b * 3 * N_;
  float sqc = (cx * cx + cy * cy) + cz * cz;         // no fma
  int found = 0, first = 0;
  for (int c = 0; c < N_ / 64; ++c) {
    int n = c * 64 + lane;
    float x = xb[n], y = xb[N_ + n], z = xb[2 * N_ + n];
    float sqx = (x * x + y * y) + z * z;             // no fma
    float dot = fmaf(cz, z, fmaf(cy, y, cx * x));    // fma chain (proven ref rounding)
    float d2 = (sqc + sqx) - 2.0f * dot;
    bool in = d2 < r2;
    unsigned long long mask = __ballot(in);
    if (mask) {
      if (found == 0) first = c * 64 + (__ffsll((long long)mask) - 1);
      int pos = found + __popcll(mask & ((1ull << lane) - 1ull));
      if (in && pos < KNB) atomicExch(&nidx[(size_t)q * KNB + pos], n);  // coherent write
      found += __popcll(mask);
      if (found >= KNB) break;
    }
  }
  if (found < KNB) {
    int fill = (found == 0) ? 0 : first;
    for (int s2 = found + lane; s2 < KNB; s2 += 64) atomicExch(&nidx[(size_t)q * KNB + s2], fill);
  }
}

// ---------------- MEGA kernel, XCD-partitioned roles -----------------------------------------
// R13 post-mortem: all three sync schemes land fps at 3990-4170 vs 3680 solo -> sync mechanics
// are NOT the cost. Remaining theory: L2/XCD pollution -- conv's streaming (feat reads + 201MB
// Z writes) runs on every XCD incl. fps's, evicting fps's step-critical working set.
// R14: role-by-XCD (bid%8 = XCD heuristic): fps = bids 0-3 (XCDs 0-3); conv = bid%8 in {4..7}
// (128 blocks, streaming confined to XCDs 4-7); bq = remaining 124 blocks on XCDs 0-3 (bq
// reads the same xyz as fps -> constructive sharing). Placement is a perf heuristic only;
// correctness is placement-independent. Sync = R12's proven scheme (batched publish, sentinel
// polls, all capped + s_sleep backoff -> failure is a visible mismatch, never a hang).
__global__ __launch_bounds__(512, 2) void mega_kernel(
    const float* __restrict__ xyz, const float* __restrict__ feat,
    float* __restrict__ newxyz, float* __restrict__ outxyz,
    int* __restrict__ nidx0, int* __restrict__ nidx1,
    float* __restrict__ Z, double* __restrict__ st3, const float* __restrict__ w10) {
  __shared__ __align__(16) char smem[98304];
  int bid = blockIdx.x, t = threadIdx.x, lane = t & 63, wid = t >> 6;

  if (bid < 4) {
    // ================= FPS role (R9-verbatim arithmetic + batched publication) ==============
#pragma clang fp contract(off)
    float* s_out = (float*)smem;                                   // 3*M floats (24576B)
    unsigned long long* s_red = (unsigned long long*)(smem + 24576);
    int* s_w = (int*)(smem + 24640);
    int b = bid;
    const float* xb = xyz + (size_t)b * 3 * N_;
    float px[32], py[32], pz[32], dd[32];
#pragma unroll
    for (int i = 0; i < 32; ++i) {
      int n = t + (i << 9);
      px[i] = xb[n]; py[i] = xb[N_ + n]; pz[i] = xb[2 * N_ + n];
      dd[i] = 1e10f;
      asm volatile("" : "+v"(px[i]), "+v"(py[i]), "+v"(pz[i]));
    }
    size_t base = (size_t)b * 3 * M_;
    float fx = xb[0], fy = xb[N_], fz = xb[2 * N_];
    if (t == 0) {
      s_out[0] = fx; s_out[M_] = fy; s_out[2 * M_] = fz;
      atomicExch(&newxyz[base], fx); atomicExch(&newxyz[base + M_], fy);
      atomicExch(&newxyz[base + 2 * M_], fz);      // step 0 immediately (bq can start)
    }
    for (int s = 1; s < M_; ++s) {
      float bv = -1.f; int bi = 0;
#pragma unroll
      for (int i = 0; i < 32; ++i) {
        float dx = px[i] - fx, dy = py[i] - fy, dz = pz[i] - fz;
        float d = (dx * dx + dy * dy) + dz * dz;   // verbatim ref arithmetic (no FMA)
        float dm = dd[i];
        if (d < dm) dm = d;
        dd[i] = dm;
        if (dm > bv) { bv = dm; bi = t + (i << 9); }
      }
      unsigned long long key =
          ((unsigned long long)__float_as_uint(bv) << 32) | (unsigned)(0xFFFFFFFFu - (unsigned)bi);
#pragma unroll
      for (int off = 1; off < 64; off <<= 1) {
        unsigned long long o = __shfl_xor(key, off);
        if (o > key) key = o;
      }
      if (lane == 0) s_red[wid] = key;
      __syncthreads();
      if (wid == 0) {
        unsigned long long k2 = (lane < 8) ? s_red[lane] : 0ull;
#pragma unroll
        for (int off = 1; off < 8; off <<= 1) {
          unsigned long long o = __shfl_xor(k2, off);
          if (o > k2) k2 = o;
        }
        if (lane == 0) *s_w = (int)(0xFFFFFFFFu - (unsigned)(k2 & 0xFFFFFFFFull));
        // batched publication: steps [s-8, s-1] -> ONE vmcnt drain per 8 steps.
        if ((s & 7) == 0 && lane < 24) {
          int st = (s - 8) + lane / 3, cd = lane % 3;
          atomicExch(&newxyz[base + (size_t)cd * M_ + st], s_out[(size_t)cd * M_ + st]);
        }
      }
      __syncthreads();
      int w = *s_w;
      fx = xb[w]; fy = xb[N_ + w]; fz = xb[2 * N_ + w];
      if (t == 0) { s_out[s] = fx; s_out[M_ + s] = fy; s_out[2 * M_ + s] = fz; }
    }
    __syncthreads();
    // tail: steps 2040..2047
    if (t < 24) {
      int st = 2040 + t / 3, cd = t % 3;
      atomicExch(&newxyz[base + (size_t)cd * M_ + st], s_out[(size_t)cd * M_ + st]);
    }
    for (int e = t; e < 3 * M_; e += 512) outxyz[base + e] = s_out[e];  // d_out copy
  } else if ((bid & 7) >= 4) {
    // ================= scale1 convL0 role: 128 blocks, XCDs 4-7 only ========================
    int convIdx = (bid >> 3) * 4 + (bid & 7) - 4;  // 0..127
    float* sx   = (float*)smem;                  // 67*64 floats
    int*   snb  = (int*)(smem + 17152);
    float* sctr = (float*)(smem + 17152 + 256);
    for (int R = convIdx; R < COLS1 / 64; R += 128) {
      __syncthreads();                           // protect snb/sx from previous record
      if (wid == 0) {
        int* p = nidx1 + (size_t)R * 64 + lane;
        int v = -1;
        for (int it = 0; it < (1 << 18); ++it) {
          v = atomicAdd(p, 0);                   // coherent read; valid entries 0..16383
          if (v != -1) break;
          __builtin_amdgcn_s_sleep(64);
        }
        snb[lane] = (v < 0) ? 0 : v;
        if (lane < 3) {                          // coords valid once nidx row complete
          int b = R >> 11, m = R & 2047;
          sctr[lane] = __uint_as_float(
              atomicAdd((unsigned*)(newxyz + ((size_t)b * 3 + lane) * M_ + m), 0u));
        }
      }
      __syncthreads();
      int b = R >> 11;
      for (int e = t; e < 67 * 64; e += 512) {
        int c = e >> 6, l = e & 63;
        int n = snb[l];
        float v;
        if (c < 3) v = xyz[((size_t)b * 3 + c) * N_ + n] - sctr[c];
        else       v = feat[((size_t)b * 64 + (c - 3)) * N_ + n];
        sx[e] = v;
      }
      __syncthreads();
      float* zr = Z + (size_t)R * ZSTRIDE;
      int part = R & 63;
      float acc[8];
      conv_sweep8<67>(w10, wid, sx, lane, acc);  // outs o = wid + 8k
#pragma unroll
      for (int k = 0; k < 8; ++k) {
        int o = wid + 8 * k;
        zr[o * 64 + lane] = acc[k];
        stat_accum(acc[k], o, 64, st3, part, lane);
      }
    }
  } else {
    // ================= BQ role: 124 blocks on XCDs 0-3 (shares fps's xyz in L2) =============
    int bqIdx = ((bid >> 3) - 1) * 4 + (bid & 3);  // bids >=8 with bid%8<4 -> 0..123
    int waveId = bqIdx * 8 + wid;
    for (int T = waveId; T < 2 * B_ * M_; T += 124 * 8) {
      int mg = T >> 1;                           // global center 0..8191
      int b = mg >> 11, m = mg & 2047;
      unsigned vv = 0;
      if (lane < 3) {
        unsigned* p = (unsigned*)(newxyz + ((size_t)b * 3 + lane) * M_ + m);
        for (int it = 0; it < (1 << 18); ++it) {
          vv = atomicAdd(p, 0u);                 // coherent read
          if (vv != 0xFFFFFFFFu) break;          // coords in [0,1) -> never NaN bits
          __builtin_amdgcn_s_sleep(64);          // long backoff: cut poll pressure 4x
        }
      }
      float cx = __uint_as_float(__shfl((int)vv, 0));
      float cy = __uint_as_float(__shfl((int)vv, 1));
      float cz = __uint_as_float(__shfl((int)vv, 2));
      if (T & 1) bq_wave<64>(xyz, nidx1, mg, b, cx, cy, cz, (float)(0.4 * 0.4), lane);
      else       bq_wave<32>(xyz, nidx0, mg, b, cx, cy, cz, (float)(0.2 * 0.2), lane);
    }
  }
}

// ---------------- stage BN(ReLU(zr)) tile -> sx, float4 path ---------------------------------
template <int CIN>
__device__ __forceinline__ void stage_bn(const float* __restrict__ zr,
                                         const float4* __restrict__ coefIn,
                                         float* sx, int t) {
  const float4* zr4 = (const float4*)zr;
  float4* sx4 = (float4*)sx;
  for (int e = t; e < CIN * 16; e += 256) {
    int c = e >> 4;
    float4 v = zr4[e];
    float4 cf = coefIn[c];
    float4 r;
    r.x = fmaxf(((v.x - cf.x) * cf.y) * cf.z + cf.w, 0.f);
    r.y = fmaxf(((v.y - cf.x) * cf.y) * cf.z + cf.w, 0.f);
    r.z = fmaxf(((v.z - cf.x) * cf.y) * cf.z + cf.w, 0.f);
    r.w = fmaxf(((v.w - cf.x) * cf.y) * cf.z + cf.w, 0.f);
    sx4[e] = r;
  }
}

// ---------------- scale0 layer 0 (post-mega, R9-proven 4-wave version) -----------------------
template <int KNB>
__global__ __launch_bounds__(256) void convL0_kernel(
    const float* __restrict__ w0, const float* __restrict__ xyz,
    const float* __restrict__ feat, const int* __restrict__ nidx,
    const float* __restrict__ newxyz, float* __restrict__ Z, double* __restrict__ stats) {
  __shared__ float sx[67 * 64];
  __shared__ int snb[64];
  int rec = blockIdx.x, t = threadIdx.x, lane = t & 63, wid = t >> 6;
  if (t < 64) snb[t] = nidx[(size_t)rec * 64 + t];
  __syncthreads();
  for (int e = t; e < 67 * 64; e += 256) {
    int c = e >> 6, l = e & 63;
    int col = rec * 64 + l;
    int b = col / (M_ * KNB);
    int rem = col - b * (M_ * KNB);
    int m = rem / KNB;
    int n = snb[l];
    float v;
    if (c < 3) v = xyz[((size_t)b * 3 + c) * N_ + n] - newxyz[((size_t)b * 3 + c) * M_ + m];
    else       v = feat[((size_t)b * 64 + (c - 3)) * N_ + n];
    sx[e] = v;
  }
  __syncthreads();
  float* zr = Z + (size_t)rec * ZSTRIDE;
  int part = rec & 63;
  float acc[8];
#pragma unroll
  for (int g = 0; g < 2; ++g) {
    int o0 = wid + 32 * g;
    conv_sweep<67, 8>(w0, o0, sx, lane, acc);
#pragma unroll
    for (int k = 0; k < 8; ++k) {
      int o = o0 + 4 * k;
      zr[o * 64 + lane] = acc[k];
      stat_accum(acc[k], o, 64, stats, part, lane);
    }
  }
}

// ---------------- mid layer: BN-stage -> conv -> in-place store + stats ----------------------
template <int CIN, int COUT>
__global__ __launch_bounds__(256) void convMid_kernel(
    const float* __restrict__ w, const float4* __restrict__ coefIn,
    float* __restrict__ Z, double* __restrict__ stats) {
  __shared__ float sx[CIN * 64];
  int rec = blockIdx.x, t = threadIdx.x, lane = t & 63, wid = t >> 6;
  float* zr = Z + (size_t)rec * ZSTRIDE;
  stage_bn<CIN>(zr, coefIn, sx, t);
  __syncthreads();
  int part = rec & 63;
  float acc[8];
#pragma unroll
  for (int g = 0; g < COUT / 32; ++g) {
    int o0 = wid + 32 * g;
    conv_sweep<CIN, 8>(w, o0, sx, lane, acc);
#pragma unroll
    for (int k = 0; k < 8; ++k) {
      int o = o0 + 4 * k;
      zr[o * 64 + lane] = acc[k];
      stat_accum(acc[k], o, COUT, stats, part, lane);
    }
  }
}

// ---------------- last layer (single pass): conv + stats + raw min/max over K ----------------
template <int CIN, int KNB>
__global__ __launch_bounds__(256) void convLast_kernel(
    const float* __restrict__ w, const float4* __restrict__ coefIn,
    const float* __restrict__ Z, double* __restrict__ stats,
    float* __restrict__ mx, float* __restrict__ mn) {
  __shared__ float sx[CIN * 64];
  int rec = blockIdx.x, t = threadIdx.x, lane = t & 63, wid = t >> 6;
  const float* zr = Z + (size_t)rec * ZSTRIDE;
  stage_bn<CIN>(zr, coefIn, sx, t);
  __syncthreads();
  int part = rec & 63;
  float acc[8];
#pragma unroll
  for (int g = 0; g < 4; ++g) {
    int o0 = wid + 32 * g;
    conv_sweep<CIN, 8>(w, o0, sx, lane, acc);
#pragma unroll
    for (int k = 0; k < 8; ++k) {
      int o = o0 + 4 * k;
      stat_accum(acc[k], o, 128, stats, part, lane);
      float vM = acc[k], vN = acc[k];
      if (KNB == 64) {
#pragma unroll
        for (int off = 1; off < 64; off <<= 1) {
          vM = fmaxf(vM, __shfl_xor(vM, off));
          vN = fminf(vN, __shfl_xor(vN, off));
        }
        if (lane == 0) {
          mx[(size_t)o * (B_ * M_) + rec] = vM;
          mn[(size_t)o * (B_ * M_) + rec] = vN;
        }
      } else {
#pragma unroll
        for (int off = 1; off < 32; off <<= 1) {
          vM = fmaxf(vM, __shfl_xor(vM, off));
          vN = fminf(vN, __shfl_xor(vN, off));
        }
        if ((lane & 31) == 0) {
          int grp = rec * 2 + (lane >> 5);
          mx[(size_t)o * (B_ * M_) + grp] = vM;
          mn[(size_t)o * (B_ * M_) + grp] = vN;
        }
      }
    }
  }
}

// ---------------- finalize: out = ReLU(fmax(BN(mx), BN(mn))), ref op order -------------------
__global__ __launch_bounds__(256) void pool_fin_kernel(
    const float* __restrict__ mx, const float* __restrict__ mn,
    const float4* __restrict__ coefOut, float* __restrict__ outFeats, int chBase) {
  int idx = blockIdx.x * 256 + threadIdx.x;     // < 128 * B*M
  int o = idx >> 13;
  int gm = idx & 8191;
  float4 cf = coefOut[o];
  float vM = mx[idx], vN = mn[idx];
  float rM = ((vM - cf.x) * cf.y) * cf.z + cf.w;
  float rN = ((vN - cf.x) * cf.y) * cf.z + cf.w;
  float z = fmaxf(fmaxf(rM, rN), 0.f);
  int b = gm >> 11, m = gm & 2047;
  outFeats[((size_t)b * 256 + chBase + o) * M_ + m] = z;
}

// ---------------- fold fp64 BN stats into per-channel (mu, rstd, g, b) ----------------
__global__ void coef_kernel(const double* __restrict__ stats, const float* __restrict__ g,
                            const float* __restrict__ bb, float4* __restrict__ coef,
                            int cout, double invcnt) {
  int ch = threadIdx.x;
  if (ch >= cout) return;
  double s1 = 0.0, s2 = 0.0;
  for (int p = 0; p < 64; ++p) {
    s1 += stats[((size_t)p * 2 + 0) * cout + ch];
    s2 += stats[((size_t)p * 2 + 1) * cout + ch];
  }
  double mean = s1 * invcnt;
  double var = s2 * invcnt - mean * mean;
  double rstd = 1.0 / sqrt(var + 1e-5);
  coef[ch] = make_float4((float)mean, (float)rstd, g[ch], bb[ch]);
}

// ---------------- launcher ----------------
extern "C" void kernel_launch(void* const* d_in, const int* in_sizes, int n_in,
                              void* d_out, int out_size, void* d_ws, size_t ws_size,
                              hipStream_t stream) {
  const float* xyz  = (const float*)d_in[0];
  const float* feat = (const float*)d_in[1];
  const float* w00 = (const float*)d_in[2],  *g00 = (const float*)d_in[3],  *b00 = (const float*)d_in[4];
  const float* w01 = (const float*)d_in[5],  *g01 = (const float*)d_in[6],  *b01 = (const float*)d_in[7];
  const float* w02 = (const float*)d_in[8],  *g02 = (const float*)d_in[9],  *b02 = (const float*)d_in[10];
  const float* w10 = (const float*)d_in[11], *g10 = (const float*)d_in[12], *b10 = (const float*)d_in[13];
  const float* w11 = (const float*)d_in[14], *g11 = (const float*)d_in[15], *b11 = (const float*)d_in[16];
  const float* w12 = (const float*)d_in[17], *g12 = (const float*)d_in[18], *b12 = (const float*)d_in[19];

  char* ws = (char*)d_ws;
  float*  newxyz = (float*)(ws + OFF_NEWXYZ);
  int*    nidx0  = (int*)(ws + OFF_NIDX0);
  int*    nidx1  = (int*)(ws + OFF_NIDX1);
  double* stats  = (double*)(ws + OFF_STATS);
  float4* coef   = (float4*)(ws + OFF_COEF);
  float*  mx0    = (float*)(ws + OFF_MNMX + 0 * MNMX_ONE);
  float*  mn0    = (float*)(ws + OFF_MNMX + 1 * MNMX_ONE);
  float*  mx1    = (float*)(ws + OFF_MNMX + 2 * MNMX_ONE);
  float*  mn1    = (float*)(ws + OFF_MNMX + 3 * MNMX_ONE);
  float*  Z      = (float*)(ws + OFF_Z);
  float* outF = (float*)d_out;
  float* outFeats = outF + (size_t)B_ * 3 * M_;

  float4* c00 = coef + 0 * 128; float4* c01 = coef + 1 * 128; float4* c02 = coef + 2 * 128;
  float4* c10 = coef + 3 * 128; float4* c11 = coef + 4 * 128; float4* c12 = coef + 5 * 128;
  double* st0 = stats + 0 * STATS_VALS; double* st1 = stats + 1 * STATS_VALS;
  double* st2 = stats + 2 * STATS_VALS; double* st3 = stats + 3 * STATS_VALS;
  double* st4 = stats + 4 * STATS_VALS; double* st5 = stats + 5 * STATS_VALS;
  int gb0 = COLS0 / 64, gb1 = COLS1 / 64;
  int gfin = (128 * B_ * M_) / 256;

  // sentinels + stats (graph-safe, re-armed every replay)
  hipMemsetAsync(ws + OFF_STATS, 0, 6 * STATS_VALS * 8, stream);
  hipMemsetAsync(newxyz, 0xFF, (size_t)B_ * 3 * M_ * 4, stream);   // NaN bits = "not ready"
  hipMemsetAsync(nidx1, 0xFF, (size_t)COLS1 * 4, stream);          // -1 = "not ready"

  // mega: fps + bq(both radii) + scale1 convL0, overlapped, XCD-partitioned
  mega_kernel<<<256, 512, 0, stream>>>(xyz, feat, newxyz, outF, nidx0, nidx1, Z, st3, w10);

  // ---- scale 1 first (Z holds its L0 output): 64->96->128 ----
  coef_kernel<<<1, 128, 0, stream>>>(st3, g10, b10, c10, 64, 1.0 / COLS1);
  convMid_kernel<64, 96><<<gb1, 256, 0, stream>>>(w11, c10, Z, st4);
  coef_kernel<<<1, 128, 0, stream>>>(st4, g11, b11, c11, 96, 1.0 / COLS1);
  convLast_kernel<96, 64><<<gb1, 256, 0, stream>>>(w12, c11, Z, st5, mx1, mn1);
  coef_kernel<<<1, 128, 0, stream>>>(st5, g12, b12, c12, 128, 1.0 / COLS1);
  pool_fin_kernel<<<gfin, 256, 0, stream>>>(mx1, mn1, c12, outFeats, 128);

  // ---- scale 0 (reuses Z after scale1 consumed it): 67->64->64->128 ----
  convL0_kernel<32><<<gb0, 256, 0, stream>>>(w00, xyz, feat, nidx0, newxyz, Z, st0);
  coef_kernel<<<1, 128, 0, stream>>>(st0, g00, b00, c00, 64, 1.0 / COLS0);
  convMid_kernel<64, 64><<<gb0, 256, 0, stream>>>(w01, c00, Z, st1);
  coef_kernel<<<1, 128, 0, stream>>>(st1, g01, b01, c01, 64, 1.0 / COLS0);
  convLast_kernel<64, 32><<<gb0, 256, 0, stream>>>(w02, c01, Z, st2, mx0, mn0);
  coef_kernel<<<1, 128, 0, stream>>>(st2, g02, b02, c02, 128, 1.0 / COLS0);
  pool_fin_kernel<<<gfin, 256, 0, stream>>>(mx0, mn0, c02, outFeats, 0);
}

// Round 15
// 4891.174 us; speedup vs baseline: 1.0485x; 1.0225x over previous
//
#include <hip/hip_runtime.h>
#include <cstdint>

// ---------------- problem constants ----------------
constexpr int B_ = 4, N_ = 16384, M_ = 2048;
constexpr int COLS0 = B_ * M_ * 32;   // 262144
constexpr int COLS1 = B_ * M_ * 64;   // 524288

// ---------------- workspace layout (bytes) ----------------
constexpr size_t OFF_NEWXYZ = 0;                                   // B*3*M fp32
constexpr size_t OFF_NIDX0  = (size_t)B_ * 3 * M_ * 4;             // 98304
constexpr size_t OFF_NIDX1  = OFF_NIDX0 + (size_t)COLS0 * 4;
constexpr size_t OFF_STATS  = OFF_NIDX1 + (size_t)COLS1 * 4;
constexpr size_t STATS_VALS = 64 * 2 * 128;                        // doubles per layer region
constexpr size_t OFF_COEF   = OFF_STATS + 6 * STATS_VALS * 8;      // 6 x 128 float4
constexpr size_t OFF_MNMX   = OFF_COEF + 6 * 128 * 16;             // 4 x (B*M*128) fp32 = 16MB
constexpr size_t MNMX_ONE   = (size_t)B_ * M_ * 128 * 4;
constexpr size_t OFF_Z      = OFF_MNMX + 4 * MNMX_ONE;
// Z: per-64-column records [rec][96 ch][64 lanes] fp32; COLS1/64 recs -> 201.3 MB (~222MB total)
constexpr int ZSTRIDE = 96 * 64;                                   // floats per record

// ---------------- FPS (closed at 3.68ms): R0 structure ---------------------------------------
// Ledger: 512thr spill-path 3680 (best); 1024thr variants 4000-4330; LDS parking 4330;
// 8-block cross-XCD split 3750-3850 (sync floor ~1.2-1.5us/step); co-resident overlap (mega)
// inflates fps to 3990-4170 regardless of sync scheme / XCD partition. Latency-bound serial
// algorithm: 2047 strictly-sequential argmax steps; not a HW roofline (occupancy 0.38%).
__global__ __launch_bounds__(512, 2) void fps_kernel(const float* __restrict__ xyz,
                                                     float* __restrict__ newxyz,
                                                     float* __restrict__ outxyz) {
#pragma clang fp contract(off)
  int b = blockIdx.x, t = threadIdx.x;
  const float* xb = xyz + (size_t)b * 3 * N_;
  float px[32], py[32], pz[32], dd[32];
#pragma unroll
  for (int i = 0; i < 32; ++i) {
    int n = t + (i << 9);
    px[i] = xb[n]; py[i] = xb[N_ + n]; pz[i] = xb[2 * N_ + n];
    dd[i] = 1e10f;
    asm volatile("" : "+v"(px[i]), "+v"(py[i]), "+v"(pz[i]));
  }
  __shared__ float s_out[3 * M_];
  __shared__ unsigned long long s_red[8];
  __shared__ int s_w;
  float fx = xb[0], fy = xb[N_], fz = xb[2 * N_];
  if (t == 0) { s_out[0] = fx; s_out[M_] = fy; s_out[2 * M_] = fz; }
  int lane = t & 63, wid = t >> 6;
  for (int s = 1; s < M_; ++s) {
    float bv = -1.f; int bi = 0;
#pragma unroll
    for (int i = 0; i < 32; ++i) {
      float dx = px[i] - fx, dy = py[i] - fy, dz = pz[i] - fz;
      float d = (dx * dx + dy * dy) + dz * dz;   // verbatim ref arithmetic (no FMA)
      float dm = dd[i];
      if (d < dm) dm = d;
      dd[i] = dm;
      if (dm > bv) { bv = dm; bi = t + (i << 9); }  // in-thread tie -> smaller n kept
    }
    unsigned long long key =
        ((unsigned long long)__float_as_uint(bv) << 32) | (unsigned)(0xFFFFFFFFu - (unsigned)bi);
#pragma unroll
    for (int off = 1; off < 64; off <<= 1) {
      unsigned long long o = __shfl_xor(key, off);
      if (o > key) key = o;
    }
    if (lane == 0) s_red[wid] = key;
    __syncthreads();
    if (wid == 0) {
      unsigned long long k2 = (lane < 8) ? s_red[lane] : 0ull;
#pragma unroll
      for (int off = 1; off < 8; off <<= 1) {
        unsigned long long o = __shfl_xor(k2, off);
        if (o > k2) k2 = o;
      }
      if (lane == 0) s_w = (int)(0xFFFFFFFFu - (unsigned)(k2 & 0xFFFFFFFFull));
    }
    __syncthreads();
    int w = s_w;
    fx = xb[w]; fy = xb[N_ + w]; fz = xb[2 * N_ + w];
    if (t == 0) { s_out[s] = fx; s_out[M_ + s] = fy; s_out[2 * M_ + s] = fz; }
  }
  __syncthreads();
  for (int e = t; e < 3 * M_; e += 512) {
    float v = s_out[e];
    newxyz[(size_t)b * 3 * M_ + e] = v;
    outxyz[(size_t)b * 3 * M_ + e] = v;
  }
}

// ---------------- ball query: wave per center, ballot-prefix, FMA dot ------------------------
template <int KNB>
__global__ __launch_bounds__(256) void bq_kernel(const float* __restrict__ xyz,
                                                 const float* __restrict__ newxyz,
                                                 int* __restrict__ nidx, float r2) {
#pragma clang fp contract(off)
  int t = threadIdx.x, lane = t & 63, wq = t >> 6;
  int q = blockIdx.x * 4 + wq;               // q < B*M
  int b = q >> 11, m = q & 2047;
  const float* xb = xyz + (size_t)b * 3 * N_;
  float cx = newxyz[((size_t)b * 3 + 0) * M_ + m];
  float cy = newxyz[((size_t)b * 3 + 1) * M_ + m];
  float cz = newxyz[((size_t)b * 3 + 2) * M_ + m];
  float sqc = (cx * cx + cy * cy) + cz * cz;         // no fma
  int found = 0, first = 0;
  for (int c = 0; c < N_ / 64; ++c) {
    int n = c * 64 + lane;
    float x = xb[n], y = xb[N_ + n], z = xb[2 * N_ + n];
    float sqx = (x * x + y * y) + z * z;             // no fma
    float dot = fmaf(cz, z, fmaf(cy, y, cx * x));    // fma chain (proven ref rounding)
    float d2 = (sqc + sqx) - 2.0f * dot;
    bool in = d2 < r2;
    unsigned long long mask = __ballot(in);
    if (mask) {
      if (found == 0) first = c * 64 + (__ffsll((long long)mask) - 1);
      int pos = found + __popcll(mask & ((1ull << lane) - 1ull));
      if (in && pos < KNB) nidx[(size_t)q * KNB + pos] = n;
      found += __popcll(mask);
      if (found >= KNB) break;                       // first K ascending == K smallest indices
    }
  }
  if (found < KNB) {
    int fill = (found == 0) ? 0 : first;
    for (int s = found + lane; s < KNB; s += 64) nidx[(size_t)q * KNB + s] = fill;
  }
}

// ---------------- per-channel stats: fp32 butterfly partials -> f64 bucketed atomics ----------
__device__ __forceinline__ void stat_accum(float acc, int o, int cout, double* stats,
                                           int part, int lane) {
  float v1 = acc, v2 = acc * acc;
#pragma unroll
  for (int off = 1; off < 64; off <<= 1) {
    v1 += __shfl_xor(v1, off);
    v2 += __shfl_xor(v2, off);
  }
  if (lane == 0) {
    atomicAdd(stats + ((size_t)part * 2 + 0) * cout + o, (double)v1);
    atomicAdd(stats + ((size_t)part * 2 + 1) * cout + o, (double)v2);
  }
}

// ---------------- conv: LDS tile + uniform sgpr weight base ----------------------------------
template <int CIN, int G>
__device__ __forceinline__ void conv_sweep(const float* __restrict__ w, int o0,
                                           const float* sx, int lane, float* acc) {
  int o0u = __builtin_amdgcn_readfirstlane(o0);       // exact: o0 is wave-uniform
  const float* wb = w + (size_t)o0u * CIN;            // SGPR base -> s_load weights
#pragma unroll
  for (int k = 0; k < G; ++k) acc[k] = 0.f;
#pragma unroll 8
  for (int c = 0; c < CIN; ++c) {
    float xv = sx[c * 64 + lane];
#pragma unroll
    for (int k = 0; k < G; ++k) acc[k] += wb[(size_t)(4 * k) * CIN + c] * xv;
  }
}

// stage BN(ReLU(zr)) tile -> sx, float4 path (Z records are 16B-aligned)
template <int CIN>
__device__ __forceinline__ void stage_bn(const float* __restrict__ zr,
                                         const float4* __restrict__ coefIn,
                                         float* sx, int t) {
  const float4* zr4 = (const float4*)zr;
  float4* sx4 = (float4*)sx;
  for (int e = t; e < CIN * 16; e += 256) {
    int c = e >> 4;
    float4 v = zr4[e];
    float4 cf = coefIn[c];
    float4 r;
    r.x = fmaxf(((v.x - cf.x) * cf.y) * cf.z + cf.w, 0.f);
    r.y = fmaxf(((v.y - cf.x) * cf.y) * cf.z + cf.w, 0.f);
    r.z = fmaxf(((v.z - cf.x) * cf.y) * cf.z + cf.w, 0.f);
    r.w = fmaxf(((v.w - cf.x) * cf.y) * cf.z + cf.w, 0.f);
    sx4[e] = r;
  }
}

// ---------------- layer 0: gather once -> LDS -> conv(67->64) + stats ------------------------
template <int KNB>
__global__ __launch_bounds__(256) void convL0_kernel(
    const float* __restrict__ w0, const float* __restrict__ xyz,
    const float* __restrict__ feat, const int* __restrict__ nidx,
    const float* __restrict__ newxyz, float* __restrict__ Z, double* __restrict__ stats) {
  __shared__ float sx[67 * 64];                 // 17152 B
  __shared__ int snb[64];
  int rec = blockIdx.x, t = threadIdx.x, lane = t & 63, wid = t >> 6;
  if (t < 64) snb[t] = nidx[(size_t)rec * 64 + t];
  __syncthreads();
  for (int e = t; e < 67 * 64; e += 256) {      // each input element fetched exactly once
    int c = e >> 6, l = e & 63;
    int col = rec * 64 + l;
    int b = col / (M_ * KNB);
    int rem = col - b * (M_ * KNB);
    int m = rem / KNB;
    int n = snb[l];
    float v;
    if (c < 3) v = xyz[((size_t)b * 3 + c) * N_ + n] - newxyz[((size_t)b * 3 + c) * M_ + m];
    else       v = feat[((size_t)b * 64 + (c - 3)) * N_ + n];
    sx[e] = v;
  }
  __syncthreads();
  float* zr = Z + (size_t)rec * ZSTRIDE;
  int part = rec & 63;
  float acc[8];
#pragma unroll
  for (int g = 0; g < 2; ++g) {                 // 16 outs/wave: o = wid + 32g + 4k
    int o0 = wid + 32 * g;
    conv_sweep<67, 8>(w0, o0, sx, lane, acc);
#pragma unroll
    for (int k = 0; k < 8; ++k) {
      int o = o0 + 4 * k;
      zr[o * 64 + lane] = acc[k];
      stat_accum(acc[k], o, 64, stats, part, lane);
    }
  }
}

// ---------------- mid layer: BN-stage -> conv -> in-place store + stats ----------------------
template <int CIN, int COUT>
__global__ __launch_bounds__(256) void convMid_kernel(
    const float* __restrict__ w, const float4* __restrict__ coefIn,
    float* __restrict__ Z, double* __restrict__ stats) {
  __shared__ float sx[CIN * 64];
  int rec = blockIdx.x, t = threadIdx.x, lane = t & 63, wid = t >> 6;
  float* zr = Z + (size_t)rec * ZSTRIDE;
  stage_bn<CIN>(zr, coefIn, sx, t);
  __syncthreads();                              // all reads done -> safe in-place overwrite
  int part = rec & 63;
  float acc[8];
#pragma unroll
  for (int g = 0; g < COUT / 32; ++g) {
    int o0 = wid + 32 * g;
    conv_sweep<CIN, 8>(w, o0, sx, lane, acc);
#pragma unroll
    for (int k = 0; k < 8; ++k) {
      int o = o0 + 4 * k;
      zr[o * 64 + lane] = acc[k];
      stat_accum(acc[k], o, COUT, stats, part, lane);
    }
  }
}

// ---------------- last layer (single pass): conv + stats + raw min/max over K ----------------
// Monotonicity (bit-exact): every BN step (-mu, *rstd>0, *g, +b) is monotone fp with fixed
// 2nd operand, so max_k ReLU(BN(z_k)) = ReLU(fmax(BN(max_k z), BN(min_k z))).
template <int CIN, int KNB>
__global__ __launch_bounds__(256) void convLast_kernel(
    const float* __restrict__ w, const float4* __restrict__ coefIn,
    const float* __restrict__ Z, double* __restrict__ stats,
    float* __restrict__ mx, float* __restrict__ mn) {
  __shared__ float sx[CIN * 64];
  int rec = blockIdx.x, t = threadIdx.x, lane = t & 63, wid = t >> 6;
  const float* zr = Z + (size_t)rec * ZSTRIDE;
  stage_bn<CIN>(zr, coefIn, sx, t);
  __syncthreads();
  int part = rec & 63;
  float acc[8];
#pragma unroll
  for (int g = 0; g < 4; ++g) {                 // 128 outs
    int o0 = wid + 32 * g;
    conv_sweep<CIN, 8>(w, o0, sx, lane, acc);
#pragma unroll
    for (int k = 0; k < 8; ++k) {
      int o = o0 + 4 * k;
      stat_accum(acc[k], o, 128, stats, part, lane);
      float vM = acc[k], vN = acc[k];
      if (KNB == 64) {
#pragma unroll
        for (int off = 1; off < 64; off <<= 1) {
          vM = fmaxf(vM, __shfl_xor(vM, off));
          vN = fminf(vN, __shfl_xor(vN, off));
        }
        if (lane == 0) {
          mx[(size_t)o * (B_ * M_) + rec] = vM;
          mn[(size_t)o * (B_ * M_) + rec] = vN;
        }
      } else {                                  // KNB == 32: two centers per wave
#pragma unroll
        for (int off = 1; off < 32; off <<= 1) {
          vM = fmaxf(vM, __shfl_xor(vM, off));
          vN = fminf(vN, __shfl_xor(vN, off));
        }
        if ((lane & 31) == 0) {
          int grp = rec * 2 + (lane >> 5);      // global center index (b*M+m)
          mx[(size_t)o * (B_ * M_) + grp] = vM;
          mn[(size_t)o * (B_ * M_) + grp] = vN;
        }
      }
    }
  }
}

// ---------------- finalize: out = ReLU(fmax(BN(mx), BN(mn))), ref op order -------------------
__global__ __launch_bounds__(256) void pool_fin_kernel(
    const float* __restrict__ mx, const float* __restrict__ mn,
    const float4* __restrict__ coefOut, float* __restrict__ outFeats, int chBase) {
  int idx = blockIdx.x * 256 + threadIdx.x;     // < 128 * B*M
  int o = idx >> 13;                            // B*M = 8192
  int gm = idx & 8191;
  float4 cf = coefOut[o];
  float vM = mx[idx], vN = mn[idx];
  float rM = ((vM - cf.x) * cf.y) * cf.z + cf.w;   // ref op order
  float rN = ((vN - cf.x) * cf.y) * cf.z + cf.w;
  float z = fmaxf(fmaxf(rM, rN), 0.f);
  int b = gm >> 11, m = gm & 2047;
  outFeats[((size_t)b * 256 + chBase + o) * M_ + m] = z;
}

// ---------------- fold fp64 BN stats into per-channel (mu, rstd, g, b) ----------------
__global__ void coef_kernel(const double* __restrict__ stats, const float* __restrict__ g,
                            const float* __restrict__ bb, float4* __restrict__ coef,
                            int cout, double invcnt) {
  int ch = threadIdx.x;
  if (ch >= cout) return;
  double s1 = 0.0, s2 = 0.0;
  for (int p = 0; p < 64; ++p) {
    s1 += stats[((size_t)p * 2 + 0) * cout + ch];
    s2 += stats[((size_t)p * 2 + 1) * cout + ch];
  }
  double mean = s1 * invcnt;
  double var = s2 * invcnt - mean * mean;
  double rstd = 1.0 / sqrt(var + 1e-5);
  coef[ch] = make_float4((float)mean, (float)rstd, g[ch], bb[ch]);
}

// ---------------- launcher ----------------
extern "C" void kernel_launch(void* const* d_in, const int* in_sizes, int n_in,
                              void* d_out, int out_size, void* d_ws, size_t ws_size,
                              hipStream_t stream) {
  const float* xyz  = (const float*)d_in[0];
  const float* feat = (const float*)d_in[1];
  const float* w00 = (const float*)d_in[2],  *g00 = (const float*)d_in[3],  *b00 = (const float*)d_in[4];
  const float* w01 = (const float*)d_in[5],  *g01 = (const float*)d_in[6],  *b01 = (const float*)d_in[7];
  const float* w02 = (const float*)d_in[8],  *g02 = (const float*)d_in[9],  *b02 = (const float*)d_in[10];
  const float* w10 = (const float*)d_in[11], *g10 = (const float*)d_in[12], *b10 = (const float*)d_in[13];
  const float* w11 = (const float*)d_in[14], *g11 = (const float*)d_in[15], *b11 = (const float*)d_in[16];
  const float* w12 = (const float*)d_in[17], *g12 = (const float*)d_in[18], *b12 = (const float*)d_in[19];

  char* ws = (char*)d_ws;
  float*  newxyz = (float*)(ws + OFF_NEWXYZ);
  int*    nidx0  = (int*)(ws + OFF_NIDX0);
  int*    nidx1  = (int*)(ws + OFF_NIDX1);
  double* stats  = (double*)(ws + OFF_STATS);
  float4* coef   = (float4*)(ws + OFF_COEF);
  float*  mx0    = (float*)(ws + OFF_MNMX + 0 * MNMX_ONE);
  float*  mn0    = (float*)(ws + OFF_MNMX + 1 * MNMX_ONE);
  float*  mx1    = (float*)(ws + OFF_MNMX + 2 * MNMX_ONE);
  float*  mn1    = (float*)(ws + OFF_MNMX + 3 * MNMX_ONE);
  float*  Z      = (float*)(ws + OFF_Z);
  float* outF = (float*)d_out;
  float* outFeats = outF + (size_t)B_ * 3 * M_;

  hipMemsetAsync(ws + OFF_STATS, 0, 6 * STATS_VALS * 8, stream);
  fps_kernel<<<B_, 512, 0, stream>>>(xyz, newxyz, outF);
  bq_kernel<32><<<(B_ * M_) / 4, 256, 0, stream>>>(xyz, newxyz, nidx0, (float)(0.2 * 0.2));
  bq_kernel<64><<<(B_ * M_) / 4, 256, 0, stream>>>(xyz, newxyz, nidx1, (float)(0.4 * 0.4));

  float4* c00 = coef + 0 * 128; float4* c01 = coef + 1 * 128; float4* c02 = coef + 2 * 128;
  float4* c10 = coef + 3 * 128; float4* c11 = coef + 4 * 128; float4* c12 = coef + 5 * 128;
  double* st0 = stats + 0 * STATS_VALS; double* st1 = stats + 1 * STATS_VALS;
  double* st2 = stats + 2 * STATS_VALS; double* st3 = stats + 3 * STATS_VALS;
  double* st4 = stats + 4 * STATS_VALS; double* st5 = stats + 5 * STATS_VALS;
  int gb0 = COLS0 / 64, gb1 = COLS1 / 64;       // one record per 256-thr block
  int gfin = (128 * B_ * M_) / 256;             // finalize grid

  // ---- scale 0 (K=32): 67->64->64->128 ----
  convL0_kernel<32><<<gb0, 256, 0, stream>>>(w00, xyz, feat, nidx0, newxyz, Z, st0);
  coef_kernel<<<1, 128, 0, stream>>>(st0, g00, b00, c00, 64, 1.0 / COLS0);
  convMid_kernel<64, 64><<<gb0, 256, 0, stream>>>(w01, c00, Z, st1);
  coef_kernel<<<1, 128, 0, stream>>>(st1, g01, b01, c01, 64, 1.0 / COLS0);
  convLast_kernel<64, 32><<<gb0, 256, 0, stream>>>(w02, c01, Z, st2, mx0, mn0);
  coef_kernel<<<1, 128, 0, stream>>>(st2, g02, b02, c02, 128, 1.0 / COLS0);
  pool_fin_kernel<<<gfin, 256, 0, stream>>>(mx0, mn0, c02, outFeats, 0);

  // ---- scale 1 (K=64): 67->64->96->128 ----
  convL0_kernel<64><<<gb1, 256, 0, stream>>>(w10, xyz, feat, nidx1, newxyz, Z, st3);
  coef_kernel<<<1, 128, 0, stream>>>(st3, g10, b10, c10, 64, 1.0 / COLS1);
  convMid_kernel<64, 96><<<gb1, 256, 0, stream>>>(w11, c10, Z, st4);
  coef_kernel<<<1, 128, 0, stream>>>(st4, g11, b11, c11, 96, 1.0 / COLS1);
  convLast_kernel<96, 64><<<gb1, 256, 0, stream>>>(w12, c11, Z, st5, mx1, mn1);
  coef_kernel<<<1, 128, 0, stream>>>(st5, g12, b12, c12, 128, 1.0 / COLS1);
  pool_fin_kernel<<<gfin, 256, 0, stream>>>(mx1, mn1, c12, outFeats, 128);
}